// Round 8
// baseline (595.558 us; speedup 1.0000x reference)
//
#include <hip/hip_runtime.h>
#include <cstdint>

// CapsuleLayer dynamic routing: B=256, R=1152, C=10, O=16, I=8, 3 iters.
// fp32 in, fp32 out. Round-8 structure: block = (c, 4 batches), 384 threads,
// each thread owns exactly 3 r-rows (1152 = 384*3) and keeps u for all 4
// batches in REGISTERS (packed bf16). W-slice read once per block, reused
// 4x -> per-CU L1/VMEM traffic drops ~4x vs round 7 (the real bottleneck:
// VALUBusy was only 26% with nothing else busy -> VMEM return/latency bound).
// b_ij never stored: with b0=0, logit_k = u . (v0 + ... + v_{k-1}).
#define BB 256
#define RR 1152
#define CC 10
#define OO 16
#define II 8
#define NT 384
#define GG 4
#define JJ 3          // r-rows per thread
#define NWAVE (NT / 64)

__device__ __forceinline__ uint32_t f2bf(float f) {
    union { float f; uint32_t i; } v; v.f = f;
    return (v.i + 0x7fffu + ((v.i >> 16) & 1u)) >> 16;   // RNE
}
__device__ __forceinline__ void unpack2(uint32_t pk, float& lo, float& hi) {
    union { uint32_t i; float f; } a, b;
    a.i = pk << 16; b.i = pk & 0xffff0000u;
    lo = a.f; hi = b.f;
}

__global__ __launch_bounds__(NT, 3)
void k_caps(const float* __restrict__ x, const float* __restrict__ W,
            float* __restrict__ out) {
    __shared__ float part[GG][NWAVE][17];
    __shared__ float wsum[GG][OO];

    const int t = threadIdx.x;
    const int c  = blockIdx.x / (BB / GG);   // c-major: 64 consecutive blocks
    const int bg = blockIdx.x % (BB / GG);   // share one 590 KB W-slice in L2
    const int b0 = bg * GG;
    const int wv = t >> 6, l = t & 63;

    uint32_t upk[GG][JJ * 8];   // u[g][r][o] as packed bf16 pairs: 96 VGPRs

    // ---- Phase 1: u[g][j][:] = W[r,c,:,:] . x[b0+g, r, :]  (regs only) ----
#pragma unroll
    for (int j = 0; j < JJ; ++j) {
        const int r = t + NT * j;
        float xg[GG][II];
#pragma unroll
        for (int g = 0; g < GG; ++g) {
            const float* xp = x + ((size_t)(b0 + g) * RR + r) * II;
            float4 x0 = *reinterpret_cast<const float4*>(xp);
            float4 x1 = *reinterpret_cast<const float4*>(xp + 4);
            xg[g][0] = x0.x; xg[g][1] = x0.y; xg[g][2] = x0.z; xg[g][3] = x0.w;
            xg[g][4] = x1.x; xg[g][5] = x1.y; xg[g][6] = x1.z; xg[g][7] = x1.w;
        }
        const float* wrow = W + ((size_t)r * CC + c) * (OO * II);
#pragma unroll
        for (int op = 0; op < 8; ++op) {    // o-pair: o = 2*op, 2*op+1
            float4 a0 = *reinterpret_cast<const float4*>(wrow + op * 16);
            float4 a1 = *reinterpret_cast<const float4*>(wrow + op * 16 + 4);
            float4 c0 = *reinterpret_cast<const float4*>(wrow + op * 16 + 8);
            float4 c1 = *reinterpret_cast<const float4*>(wrow + op * 16 + 12);
#pragma unroll
            for (int g = 0; g < GG; ++g) {
                float lo = 0.f, hi = 0.f;
                lo = fmaf(a0.x, xg[g][0], lo); lo = fmaf(a0.y, xg[g][1], lo);
                lo = fmaf(a0.z, xg[g][2], lo); lo = fmaf(a0.w, xg[g][3], lo);
                lo = fmaf(a1.x, xg[g][4], lo); lo = fmaf(a1.y, xg[g][5], lo);
                lo = fmaf(a1.z, xg[g][6], lo); lo = fmaf(a1.w, xg[g][7], lo);
                hi = fmaf(c0.x, xg[g][0], hi); hi = fmaf(c0.y, xg[g][1], hi);
                hi = fmaf(c0.z, xg[g][2], hi); hi = fmaf(c0.w, xg[g][3], hi);
                hi = fmaf(c1.x, xg[g][4], hi); hi = fmaf(c1.y, xg[g][5], hi);
                hi = fmaf(c1.z, xg[g][6], hi); hi = fmaf(c1.w, xg[g][7], hi);
                upk[g][j * 8 + op] = f2bf(lo) | (f2bf(hi) << 16);
            }
        }
    }

    // ---- Phase 2: three routing passes, u from registers ----
    // pass 0: uniform softmax (den = R). pass 1: w = v0. pass 2: w = v0+v1.
    for (int pass = 0; pass < 3; ++pass) {
#pragma unroll
        for (int g = 0; g < GG; ++g) {
            float wreg[OO];
            if (pass > 0) {
#pragma unroll
                for (int k = 0; k < OO; ++k) wreg[k] = wsum[g][k];  // broadcast
            }
            float num[OO];
#pragma unroll
            for (int k = 0; k < OO; ++k) num[k] = 0.f;
            float den = 0.f;

#pragma unroll
            for (int j = 0; j < JJ; ++j) {
                float ur[OO];
#pragma unroll
                for (int op = 0; op < 8; ++op)
                    unpack2(upk[g][j * 8 + op], ur[2 * op], ur[2 * op + 1]);
                if (pass == 0) {
#pragma unroll
                    for (int k = 0; k < OO; ++k) num[k] += ur[k];
                } else {
                    float lg = 0.f;
#pragma unroll
                    for (int k = 0; k < OO; ++k) lg = fmaf(ur[k], wreg[k], lg);
                    float e = __expf(lg);   // |logit| <~ 40: fp32-safe
                    den += e;
#pragma unroll
                    for (int k = 0; k < OO; ++k) num[k] = fmaf(e, ur[k], num[k]);
                }
            }

            // 64-lane butterfly -> lane 0 holds wave totals
#pragma unroll
            for (int m = 1; m < 64; m <<= 1) {
#pragma unroll
                for (int k = 0; k < OO; ++k) num[k] += __shfl_xor(num[k], m);
                if (pass) den += __shfl_xor(den, m);
            }
            if (l == 0) {
#pragma unroll
                for (int k = 0; k < OO; ++k) part[g][wv][k] = num[k];
                part[g][wv][16] = den;
            }
        }
        __syncthreads();

        if (t < GG * OO) {   // wave 0: g = t>>4, o = t&15
            const int g = t >> 4, o = t & 15;
            float nf = 0.f, df = 0.f;
#pragma unroll
            for (int w = 0; w < NWAVE; ++w) {
                nf += part[g][w][o];
                df += part[g][w][16];
            }
            if (pass == 0) df = (float)RR;   // softmax(0) = 1/R
            float s = nf / df;
            float ss = s * s;                 // squash over the 16-lane o-group
            ss += __shfl_xor(ss, 1);
            ss += __shfl_xor(ss, 2);
            ss += __shfl_xor(ss, 4);
            ss += __shfl_xor(ss, 8);
            float v = s * (ss / ((1.0f + ss) * sqrtf(ss + 1e-7f)));
            if (pass == 2)
                out[((size_t)(b0 + g) * CC + c) * OO + o] = v;
            else
                wsum[g][o] = pass ? (wsum[g][o] + v) : v;
        }
        __syncthreads();
    }
}

extern "C" void kernel_launch(void* const* d_in, const int* in_sizes, int n_in,
                              void* d_out, int out_size, void* d_ws, size_t ws_size,
                              hipStream_t stream) {
    const float* x = (const float*)d_in[0];  // (B,R,I) fp32
    const float* W = (const float*)d_in[1];  // (R,C,O,I) fp32
    if (n_in >= 2 && in_sizes[0] == RR * CC * OO * II &&
        in_sizes[1] == BB * RR * II) {
        const float* tmp = x; x = W; W = tmp;
    }
    float* out = (float*)d_out;              // (B,1,C,O,1) fp32

    k_caps<<<CC * (BB / GG), NT, 0, stream>>>(x, W, out);
}

// Round 9
// 474.723 us; speedup vs baseline: 1.2545x; 1.2545x over previous
//
#include <hip/hip_runtime.h>
#include <cstdint>

// CapsuleLayer dynamic routing: B=256, R=1152, C=10, O=16, I=8, 3 iters.
// fp32 in, fp32 out. Register-resident u: block = (c, 2 batches), 384
// threads, each thread owns 3 r-rows x 2 batches of u as packed bf16
// (48 VGPRs). W-slice read once per block (reused 2x). NO min-occupancy
// launch bound: round 8 proved forcing waves/EU makes the allocator spill
// upk to scratch (WRITE_SIZE 0.16 -> 497 MB, 5x regression). b_ij never
// stored: with b0=0, logit_k = u . (v0 + ... + v_{k-1}).
#define BB 256
#define RR 1152
#define CC 10
#define OO 16
#define II 8
#define NT 384
#define GG 2
#define JJ 3          // r-rows per thread (1152 = 384*3)
#define NWAVE (NT / 64)

__device__ __forceinline__ uint32_t f2bf(float f) {
    union { float f; uint32_t i; } v; v.f = f;
    return (v.i + 0x7fffu + ((v.i >> 16) & 1u)) >> 16;   // RNE
}
__device__ __forceinline__ void unpack2(uint32_t pk, float& lo, float& hi) {
    union { uint32_t i; float f; } a, b;
    a.i = pk << 16; b.i = pk & 0xffff0000u;
    lo = a.f; hi = b.f;
}

__global__ __launch_bounds__(NT)
void k_caps(const float* __restrict__ x, const float* __restrict__ W,
            float* __restrict__ out) {
    __shared__ float part[GG][NWAVE][17];
    __shared__ float wsum[GG][OO];

    const int t = threadIdx.x;
    const int c  = blockIdx.x / (BB / GG);   // c-major: 128 consecutive blocks
    const int bg = blockIdx.x % (BB / GG);   // share one 590 KB W-slice in L2
    const int b0 = bg * GG;
    const int wv = t >> 6, l = t & 63;

    uint32_t upk[GG][JJ * 8];   // u[g][j][o-pair] packed bf16: 48 VGPRs

    // ---- Phase 1: u = W[r,c,:,:] . x[b,r,:]  (registers only) ----
#pragma unroll
    for (int j = 0; j < JJ; ++j) {
        const int r = t + NT * j;
        float xg[GG][II];
#pragma unroll
        for (int g = 0; g < GG; ++g) {
            const float* xp = x + ((size_t)(b0 + g) * RR + r) * II;
            float4 x0 = *reinterpret_cast<const float4*>(xp);
            float4 x1 = *reinterpret_cast<const float4*>(xp + 4);
            xg[g][0] = x0.x; xg[g][1] = x0.y; xg[g][2] = x0.z; xg[g][3] = x0.w;
            xg[g][4] = x1.x; xg[g][5] = x1.y; xg[g][6] = x1.z; xg[g][7] = x1.w;
        }
        const float* wrow = W + ((size_t)r * CC + c) * (OO * II);
#pragma unroll
        for (int op = 0; op < 8; ++op) {    // o = 2*op, 2*op+1
            float4 a0 = *reinterpret_cast<const float4*>(wrow + op * 16);
            float4 a1 = *reinterpret_cast<const float4*>(wrow + op * 16 + 4);
            float4 c0 = *reinterpret_cast<const float4*>(wrow + op * 16 + 8);
            float4 c1 = *reinterpret_cast<const float4*>(wrow + op * 16 + 12);
#pragma unroll
            for (int g = 0; g < GG; ++g) {
                float lo = 0.f, hi = 0.f;
                lo = fmaf(a0.x, xg[g][0], lo); lo = fmaf(a0.y, xg[g][1], lo);
                lo = fmaf(a0.z, xg[g][2], lo); lo = fmaf(a0.w, xg[g][3], lo);
                lo = fmaf(a1.x, xg[g][4], lo); lo = fmaf(a1.y, xg[g][5], lo);
                lo = fmaf(a1.z, xg[g][6], lo); lo = fmaf(a1.w, xg[g][7], lo);
                hi = fmaf(c0.x, xg[g][0], hi); hi = fmaf(c0.y, xg[g][1], hi);
                hi = fmaf(c0.z, xg[g][2], hi); hi = fmaf(c0.w, xg[g][3], hi);
                hi = fmaf(c1.x, xg[g][4], hi); hi = fmaf(c1.y, xg[g][5], hi);
                hi = fmaf(c1.z, xg[g][6], hi); hi = fmaf(c1.w, xg[g][7], hi);
                upk[g][j * 8 + op] = f2bf(lo) | (f2bf(hi) << 16);
            }
        }
    }

    // ---- Phase 2: three routing passes, u from registers ----
    for (int pass = 0; pass < 3; ++pass) {
#pragma unroll
        for (int g = 0; g < GG; ++g) {
            float wreg[OO];
            if (pass > 0) {
#pragma unroll
                for (int k = 0; k < OO; ++k) wreg[k] = wsum[g][k];  // broadcast
            }
            float num[OO];
#pragma unroll
            for (int k = 0; k < OO; ++k) num[k] = 0.f;
            float den = 0.f;

#pragma unroll
            for (int j = 0; j < JJ; ++j) {
                float ur[OO];
#pragma unroll
                for (int op = 0; op < 8; ++op)
                    unpack2(upk[g][j * 8 + op], ur[2 * op], ur[2 * op + 1]);
                if (pass == 0) {
#pragma unroll
                    for (int k = 0; k < OO; ++k) num[k] += ur[k];
                } else {
                    float lg = 0.f;
#pragma unroll
                    for (int k = 0; k < OO; ++k) lg = fmaf(ur[k], wreg[k], lg);
                    float e = __expf(lg);   // |logit| <~ 40: fp32-safe
                    den += e;
#pragma unroll
                    for (int k = 0; k < OO; ++k) num[k] = fmaf(e, ur[k], num[k]);
                }
            }

#pragma unroll
            for (int m = 1; m < 64; m <<= 1) {
#pragma unroll
                for (int k = 0; k < OO; ++k) num[k] += __shfl_xor(num[k], m);
                if (pass) den += __shfl_xor(den, m);
            }
            if (l == 0) {
#pragma unroll
                for (int k = 0; k < OO; ++k) part[g][wv][k] = num[k];
                part[g][wv][16] = den;
            }
        }
        __syncthreads();

        if (t < GG * OO) {   // wave 0: g = t>>4, o = t&15
            const int g = t >> 4, o = t & 15;
            float nf = 0.f, df = 0.f;
#pragma unroll
            for (int w = 0; w < NWAVE; ++w) {
                nf += part[g][w][o];
                df += part[g][w][16];
            }
            if (pass == 0) df = (float)RR;   // softmax(0) = 1/R
            float s = nf / df;
            float ss = s * s;                 // squash over 16-lane o-group
            ss += __shfl_xor(ss, 1);
            ss += __shfl_xor(ss, 2);
            ss += __shfl_xor(ss, 4);
            ss += __shfl_xor(ss, 8);
            float v = s * (ss / ((1.0f + ss) * sqrtf(ss + 1e-7f)));
            if (pass == 2)
                out[((size_t)(b0 + g) * CC + c) * OO + o] = v;
            else
                wsum[g][o] = pass ? (wsum[g][o] + v) : v;
        }
        __syncthreads();
    }
}

extern "C" void kernel_launch(void* const* d_in, const int* in_sizes, int n_in,
                              void* d_out, int out_size, void* d_ws, size_t ws_size,
                              hipStream_t stream) {
    const float* x = (const float*)d_in[0];  // (B,R,I) fp32
    const float* W = (const float*)d_in[1];  // (R,C,O,I) fp32
    if (n_in >= 2 && in_sizes[0] == RR * CC * OO * II &&
        in_sizes[1] == BB * RR * II) {
        const float* tmp = x; x = W; W = tmp;
    }
    float* out = (float*)d_out;              // (B,1,C,O,1) fp32

    k_caps<<<CC * (BB / GG), NT, 0, stream>>>(x, W, out);
}

// Round 10
// 147.309 us; speedup vs baseline: 4.0429x; 3.2226x over previous
//
#include <hip/hip_runtime.h>
#include <cstdint>

// CapsuleLayer dynamic routing: B=256, R=1152, C=10, O=16, I=8, 3 iters.
// fp32 in, fp32 out. Block = (c, 2 batches), 384 threads. u for both
// batches lives in DYNAMIC LDS (76 KB, 2 blocks/CU), packed bf16 pairs,
// column-major with p-stride 1189 (=5 mod 32: conflict-free-ish both ways).
// W-slice read once per block, reused for 2 batches (halves round-7's
// per-CU L1 W traffic). Pass 0 fused into phase 1. NO persistent per-thread
// u array (rounds 8/9: compiler spills it -> 500-640 MB scratch traffic).
// b_ij never stored: with b0=0, logit_k = u . (v0 + ... + v_{k-1}).
#define BB 256
#define RR 1152
#define CC 10
#define OO 16
#define II 8
#define NT 384
#define GG 2
#define NWAVE (NT / 64)
#define PSTR 1189          // p-row stride in words; 1189 % 32 == 5

__device__ __forceinline__ uint32_t f2bf(float f) {
    union { float f; uint32_t i; } v; v.f = f;
    return (v.i + 0x7fffu + ((v.i >> 16) & 1u)) >> 16;   // RNE
}
__device__ __forceinline__ void unpack2(uint32_t pk, float& lo, float& hi) {
    union { uint32_t i; float f; } a, b;
    a.i = pk << 16; b.i = pk & 0xffff0000u;
    lo = a.f; hi = b.f;
}
__device__ __forceinline__ float dot8(float4 a, float4 b, float4 xa, float4 xb) {
    float s = 0.f;
    s = fmaf(a.x, xa.x, s); s = fmaf(a.y, xa.y, s);
    s = fmaf(a.z, xa.z, s); s = fmaf(a.w, xa.w, s);
    s = fmaf(b.x, xb.x, s); s = fmaf(b.y, xb.y, s);
    s = fmaf(b.z, xb.z, s); s = fmaf(b.w, xb.w, s);
    return s;
}

__global__ __launch_bounds__(NT)
void k_caps(const float* __restrict__ x, const float* __restrict__ W,
            float* __restrict__ out) {
    extern __shared__ uint32_t u2[];          // [GG][8][PSTR] packed bf16 pairs
    __shared__ float part[NWAVE][GG][17];
    __shared__ float p0s[NWAVE][8][GG][2];    // [wv][p][g][half]
    __shared__ float wsum[GG][OO];

    const int t = threadIdx.x;
    const int c  = blockIdx.x / (BB / GG);    // c-major: 128 blocks share W-slice
    const int b0 = (blockIdx.x % (BB / GG)) * GG;
    const int wv = t >> 6, l = t & 63;
    const int rg = t >> 3, p = t & 7;         // phase 1: 48 r-rows x 8 o-pairs

    uint32_t* uA = u2;                        // batch b0
    uint32_t* uB = u2 + 8 * PSTR;             // batch b0+1

    // ---- Phase 1: u[r,2p:2p+2] for both batches -> LDS; fused pass-0 sums ----
    float s00 = 0.f, s01 = 0.f, s10 = 0.f, s11 = 0.f;
#pragma unroll 2
    for (int it = 0; it < RR / 48; ++it) {
        const int r = it * 48 + rg;
        const float* wp = W + (((size_t)r * CC + c) * OO + 2 * p) * II;
        float4 a0 = *reinterpret_cast<const float4*>(wp);
        float4 a1 = *reinterpret_cast<const float4*>(wp + 4);
        float4 c0 = *reinterpret_cast<const float4*>(wp + 8);
        float4 c1 = *reinterpret_cast<const float4*>(wp + 12);
        const float* xp0 = x + ((size_t)b0 * RR + r) * II;
        const float* xp1 = xp0 + (size_t)RR * II;
        float4 x00 = *reinterpret_cast<const float4*>(xp0);
        float4 x01 = *reinterpret_cast<const float4*>(xp0 + 4);
        float4 x10 = *reinterpret_cast<const float4*>(xp1);
        float4 x11 = *reinterpret_cast<const float4*>(xp1 + 4);
        float lo0 = dot8(a0, a1, x00, x01);   // o=2p,   g=0
        float hi0 = dot8(c0, c1, x00, x01);   // o=2p+1, g=0
        float lo1 = dot8(a0, a1, x10, x11);   // o=2p,   g=1
        float hi1 = dot8(c0, c1, x10, x11);   // o=2p+1, g=1
        s00 += lo0; s01 += hi0; s10 += lo1; s11 += hi1;
        uA[p * PSTR + r] = f2bf(lo0) | (f2bf(hi0) << 16);
        uB[p * PSTR + r] = f2bf(lo1) | (f2bf(hi1) << 16);
    }
    // reduce pass-0 partials over the 8 r-lanes sharing p (masks 8,16,32)
#pragma unroll
    for (int m = 8; m < 64; m <<= 1) {
        s00 += __shfl_xor(s00, m); s01 += __shfl_xor(s01, m);
        s10 += __shfl_xor(s10, m); s11 += __shfl_xor(s11, m);
    }
    if (l < 8) {
        p0s[wv][l][0][0] = s00; p0s[wv][l][0][1] = s01;
        p0s[wv][l][1][0] = s10; p0s[wv][l][1][1] = s11;
    }
    __syncthreads();

    if (t < GG * OO) {   // g = t>>4, o = t&15 (wave 0)
        const int g = t >> 4, o = t & 15;
        float s = 0.f;
#pragma unroll
        for (int w = 0; w < NWAVE; ++w) s += p0s[w][o >> 1][g][o & 1];
        s *= (1.0f / RR);                     // softmax(0) = 1/R
        float ss = s * s;                     // squash over 16-lane o-group
        ss += __shfl_xor(ss, 1); ss += __shfl_xor(ss, 2);
        ss += __shfl_xor(ss, 4); ss += __shfl_xor(ss, 8);
        wsum[g][o] = s * (ss / ((1.0f + ss) * sqrtf(ss + 1e-7f)));  // v0
    }
    __syncthreads();

    // ---- Phase 2: passes 1 and 2 from LDS ----
    for (int pass = 1; pass < 3; ++pass) {
#pragma unroll
        for (int g = 0; g < GG; ++g) {
            const uint32_t* ug = g ? uB : uA;
            float wreg[OO];
#pragma unroll
            for (int k = 0; k < OO; ++k) wreg[k] = wsum[g][k];  // broadcast
            float num[OO];
#pragma unroll
            for (int k = 0; k < OO; ++k) num[k] = 0.f;
            float den = 0.f;

#pragma unroll
            for (int k = 0; k < 3; ++k) {
                const int r = t + NT * k;
                float ur[OO];
#pragma unroll
                for (int pp = 0; pp < 8; ++pp)  // bank = (5pp + r)%32: 2-way, free
                    unpack2(ug[pp * PSTR + r], ur[2 * pp], ur[2 * pp + 1]);
                float lg = 0.f;
#pragma unroll
                for (int k2 = 0; k2 < OO; ++k2) lg = fmaf(ur[k2], wreg[k2], lg);
                float e = __expf(lg);   // |logit| <~ 40: fp32-safe
                den += e;
#pragma unroll
                for (int k2 = 0; k2 < OO; ++k2) num[k2] = fmaf(e, ur[k2], num[k2]);
            }

#pragma unroll
            for (int m = 1; m < 64; m <<= 1) {
#pragma unroll
                for (int k = 0; k < OO; ++k) num[k] += __shfl_xor(num[k], m);
                den += __shfl_xor(den, m);
            }
            if (l == 0) {
#pragma unroll
                for (int k = 0; k < OO; ++k) part[wv][g][k] = num[k];
                part[wv][g][16] = den;
            }
        }
        __syncthreads();

        if (t < GG * OO) {
            const int g = t >> 4, o = t & 15;
            float nf = 0.f, df = 0.f;
#pragma unroll
            for (int w = 0; w < NWAVE; ++w) {
                nf += part[w][g][o];
                df += part[w][g][16];
            }
            float s = nf / df;
            float ss = s * s;
            ss += __shfl_xor(ss, 1); ss += __shfl_xor(ss, 2);
            ss += __shfl_xor(ss, 4); ss += __shfl_xor(ss, 8);
            float v = s * (ss / ((1.0f + ss) * sqrtf(ss + 1e-7f)));
            if (pass == 2)
                out[((size_t)(b0 + g) * CC + c) * OO + o] = v;
            else
                wsum[g][o] += v;
        }
        __syncthreads();
    }
}

extern "C" void kernel_launch(void* const* d_in, const int* in_sizes, int n_in,
                              void* d_out, int out_size, void* d_ws, size_t ws_size,
                              hipStream_t stream) {
    const float* x = (const float*)d_in[0];  // (B,R,I) fp32
    const float* W = (const float*)d_in[1];  // (R,C,O,I) fp32
    if (n_in >= 2 && in_sizes[0] == RR * CC * OO * II &&
        in_sizes[1] == BB * RR * II) {
        const float* tmp = x; x = W; W = tmp;
    }
    float* out = (float*)d_out;              // (B,1,C,O,1) fp32

    const size_t dyn_lds = (size_t)GG * 8 * PSTR * 4;   // 76,096 B
    k_caps<<<CC * (BB / GG), NT, dyn_lds, stream>>>(x, W, out);
}